// Round 1
// baseline (841.537 us; speedup 1.0000x reference)
//
#include <hip/hip_runtime.h>
#include <hip/hip_bf16.h>

#define NHEAD 8
#define CDIM 12
#define DMODEL 96

// ---------------- GEMM: H[N,96] = X[N,K] @ W[K,96] ----------------
// block = 192 threads: c = t%96, y = t/96 (0/1). Block computes 16 nodes.
// X tile staged transposed in LDS (broadcast reads), W staged in 32-row chunks.
template<int K>
__global__ __launch_bounds__(192) void gemm_att_kernel(
    const float* __restrict__ X, const float* __restrict__ W,
    float* __restrict__ H, int N)
{
    __shared__ float xs[K][16];
    __shared__ float wsh[32 * 96];
    const int t = threadIdx.x;
    const int c = t % 96;
    const int y = t / 96;
    const int n0 = blockIdx.x * 16;

    constexpr int KQ = K / 4;
    for (int e = t; e < 16 * KQ; e += 192) {
        int i = e / KQ, kq = e % KQ;
        int n = n0 + i;
        float4 v = make_float4(0.f, 0.f, 0.f, 0.f);
        if (n < N) v = ((const float4*)(X + (size_t)n * K))[kq];
        xs[kq * 4 + 0][i] = v.x;
        xs[kq * 4 + 1][i] = v.y;
        xs[kq * 4 + 2][i] = v.z;
        xs[kq * 4 + 3][i] = v.w;
    }

    float acc[8] = {0.f,0.f,0.f,0.f,0.f,0.f,0.f,0.f};
    for (int k0 = 0; k0 < K; k0 += 32) {
        __syncthreads();   // protect wsh (and xs on first iter)
        for (int e = t; e < 768; e += 192)
            ((float4*)wsh)[e] = ((const float4*)(W + (size_t)k0 * 96))[e];
        __syncthreads();
#pragma unroll
        for (int kk = 0; kk < 32; ++kk) {
            int k = k0 + kk;
            float w = wsh[kk * 96 + c];
            float4 xa = *(const float4*)&xs[k][y * 8];
            float4 xb = *(const float4*)&xs[k][y * 8 + 4];
            acc[0] = fmaf(xa.x, w, acc[0]);
            acc[1] = fmaf(xa.y, w, acc[1]);
            acc[2] = fmaf(xa.z, w, acc[2]);
            acc[3] = fmaf(xa.w, w, acc[3]);
            acc[4] = fmaf(xb.x, w, acc[4]);
            acc[5] = fmaf(xb.y, w, acc[5]);
            acc[6] = fmaf(xb.z, w, acc[6]);
            acc[7] = fmaf(xb.w, w, acc[7]);
        }
    }
#pragma unroll
    for (int j = 0; j < 8; ++j) {
        int n = n0 + y * 8 + j;
        if (n < N) H[(size_t)n * 96 + c] = acc[j];
    }
}

// ---------------- per-node attention coefficients ----------------
__global__ void att_kernel(const float* __restrict__ H,
                           const float* __restrict__ att_s,
                           const float* __restrict__ att_d,
                           float* __restrict__ a_s, float* __restrict__ a_d, int N)
{
    int t = blockIdx.x * blockDim.x + threadIdx.x;  // n*8 + h
    if (t >= N * NHEAD) return;
    int n = t >> 3, hh = t & 7;
    const float* hp = H + (size_t)n * DMODEL + hh * CDIM;
    float ss = 0.f, sd = 0.f;
#pragma unroll
    for (int ci = 0; ci < CDIM; ++ci) {
        float v = hp[ci];
        ss = fmaf(v, att_s[hh * CDIM + ci], ss);
        sd = fmaf(v, att_d[hh * CDIM + ci], sd);
    }
    a_s[t] = ss;
    a_d[t] = sd;
}

// ---------------- edge pass 1: e_exp + denom ----------------
__global__ void edge1_kernel(const int* __restrict__ srci, const int* __restrict__ dsti,
                             const float* __restrict__ a_s, const float* __restrict__ a_d,
                             float* __restrict__ eexp, float* __restrict__ denom,
                             int E0, int Etot)
{
    int t = blockIdx.x * blockDim.x + threadIdx.x;  // edge*8 + h
    if (t >= Etot * NHEAD) return;
    int e = t >> 3, hh = t & 7;
    int s, d;
    if (e < E0) { s = srci[e]; d = dsti[e]; }
    else        { s = d = e - E0; }
    float v = a_s[s * NHEAD + hh] + a_d[d * NHEAD + hh];
    v = v > 0.f ? v : 0.2f * v;          // leaky_relu, slope 0.2
    float ex = __expf(v);                // no max-subtraction (see analysis)
    eexp[t] = ex;
    atomicAdd(&denom[d * NHEAD + hh], ex);
}

// ---------------- edge pass 2: weighted message aggregation ----------------
__global__ __launch_bounds__(384) void edge2_kernel(
    const int* __restrict__ srci, const int* __restrict__ dsti,
    const float* __restrict__ H, const float* __restrict__ eexp,
    const float* __restrict__ denom, float* __restrict__ accum,
    int E0, int Etot)
{
    int sub = threadIdx.x / 96;          // 4 edges per block
    int c = threadIdx.x % 96;
    int e = blockIdx.x * 4 + sub;
    if (e >= Etot) return;
    int s, d;
    if (e < E0) { s = srci[e]; d = dsti[e]; }
    else        { s = d = e - E0; }
    int hh = c / CDIM;
    float alpha = eexp[e * NHEAD + hh] / (denom[d * NHEAD + hh] + 1e-16f);
    float v = H[(size_t)s * DMODEL + c] * alpha;
    atomicAdd(&accum[(size_t)d * DMODEL + c], v);
}

// ---------------- finalize: relu(accum + bias) ----------------
__global__ void finalize_kernel(const float* __restrict__ accum,
                                const float* __restrict__ bias,
                                float* __restrict__ out, int N)
{
    int t = blockIdx.x * blockDim.x + threadIdx.x;  // n*96 + c
    if (t >= N * DMODEL) return;
    int c = t % DMODEL;
    float v = accum[t] + bias[c];
    out[t] = v > 0.f ? v : 0.f;
}

extern "C" void kernel_launch(void* const* d_in, const int* in_sizes, int n_in,
                              void* d_out, int out_size, void* d_ws, size_t ws_size,
                              hipStream_t stream) {
    const float* x   = (const float*)d_in[0];
    const int*   ei  = (const int*)d_in[1];
    const float* W1  = (const float*)d_in[2];
    const float* as1 = (const float*)d_in[3];
    const float* ad1 = (const float*)d_in[4];
    const float* b1  = (const float*)d_in[5];
    const float* W2  = (const float*)d_in[6];
    const float* as2 = (const float*)d_in[7];
    const float* ad2 = (const float*)d_in[8];
    const float* b2  = (const float*)d_in[9];

    const int N    = in_sizes[0] / 128;   // 50000
    const int E0   = in_sizes[1] / 2;     // 800000
    const int Etot = E0 + N;              // with self-loops
    const int* srci = ei;
    const int* dsti = ei + E0;

    float* ws  = (float*)d_ws;
    float* H   = ws;                         // N*96
    float* H1  = H   + (size_t)N * DMODEL;   // N*96
    float* ACC = H1  + (size_t)N * DMODEL;   // N*96
    float* AS  = ACC + (size_t)N * DMODEL;   // N*8
    float* AD  = AS  + (size_t)N * NHEAD;    // N*8
    float* DEN = AD  + (size_t)N * NHEAD;    // N*8
    float* EE  = DEN + (size_t)N * NHEAD;    // Etot*8
    float* OUT = (float*)d_out;

    const int gemm_grid = (N + 15) / 16;
    const int att_grid  = (N * NHEAD + 255) / 256;
    const int e1_grid   = (Etot * NHEAD + 255) / 256;
    const int e2_grid   = (Etot + 3) / 4;
    const int fin_grid  = (N * DMODEL + 255) / 256;

    // ---------- layer 1 ----------
    hipMemsetAsync(DEN, 0, (size_t)N * NHEAD * sizeof(float), stream);
    hipMemsetAsync(ACC, 0, (size_t)N * DMODEL * sizeof(float), stream);
    gemm_att_kernel<128><<<gemm_grid, 192, 0, stream>>>(x, W1, H, N);
    att_kernel<<<att_grid, 256, 0, stream>>>(H, as1, ad1, AS, AD, N);
    edge1_kernel<<<e1_grid, 256, 0, stream>>>(srci, dsti, AS, AD, EE, DEN, E0, Etot);
    edge2_kernel<<<e2_grid, 384, 0, stream>>>(srci, dsti, H, EE, DEN, ACC, E0, Etot);
    finalize_kernel<<<fin_grid, 256, 0, stream>>>(ACC, b1, H1, N);

    // ---------- layer 2 ----------
    hipMemsetAsync(DEN, 0, (size_t)N * NHEAD * sizeof(float), stream);
    hipMemsetAsync(ACC, 0, (size_t)N * DMODEL * sizeof(float), stream);
    gemm_att_kernel<96><<<gemm_grid, 192, 0, stream>>>(H1, W2, H, N);
    att_kernel<<<att_grid, 256, 0, stream>>>(H, as2, ad2, AS, AD, N);
    edge1_kernel<<<e1_grid, 256, 0, stream>>>(srci, dsti, AS, AD, EE, DEN, E0, Etot);
    edge2_kernel<<<e2_grid, 384, 0, stream>>>(srci, dsti, H, EE, DEN, ACC, E0, Etot);
    finalize_kernel<<<fin_grid, 256, 0, stream>>>(ACC, b2, OUT, N);
}

// Round 2
// 554.788 us; speedup vs baseline: 1.5169x; 1.5169x over previous
//
#include <hip/hip_runtime.h>
#include <hip/hip_bf16.h>

#define NHEAD 8
#define CDIM 12
#define DMODEL 96

// ---------------- GEMM: H[N,96] = X[N,K] @ W[K,96] ----------------
template<int K>
__global__ __launch_bounds__(192) void gemm_att_kernel(
    const float* __restrict__ X, const float* __restrict__ W,
    float* __restrict__ H, int N)
{
    __shared__ float xs[K][16];
    __shared__ float wsh[32 * 96];
    const int t = threadIdx.x;
    const int c = t % 96;
    const int y = t / 96;
    const int n0 = blockIdx.x * 16;

    constexpr int KQ = K / 4;
    for (int e = t; e < 16 * KQ; e += 192) {
        int i = e / KQ, kq = e % KQ;
        int n = n0 + i;
        float4 v = make_float4(0.f, 0.f, 0.f, 0.f);
        if (n < N) v = ((const float4*)(X + (size_t)n * K))[kq];
        xs[kq * 4 + 0][i] = v.x;
        xs[kq * 4 + 1][i] = v.y;
        xs[kq * 4 + 2][i] = v.z;
        xs[kq * 4 + 3][i] = v.w;
    }

    float acc[8] = {0.f,0.f,0.f,0.f,0.f,0.f,0.f,0.f};
    for (int k0 = 0; k0 < K; k0 += 32) {
        __syncthreads();
        for (int e = t; e < 768; e += 192)
            ((float4*)wsh)[e] = ((const float4*)(W + (size_t)k0 * 96))[e];
        __syncthreads();
#pragma unroll
        for (int kk = 0; kk < 32; ++kk) {
            int k = k0 + kk;
            float w = wsh[kk * 96 + c];
            float4 xa = *(const float4*)&xs[k][y * 8];
            float4 xb = *(const float4*)&xs[k][y * 8 + 4];
            acc[0] = fmaf(xa.x, w, acc[0]);
            acc[1] = fmaf(xa.y, w, acc[1]);
            acc[2] = fmaf(xa.z, w, acc[2]);
            acc[3] = fmaf(xa.w, w, acc[3]);
            acc[4] = fmaf(xb.x, w, acc[4]);
            acc[5] = fmaf(xb.y, w, acc[5]);
            acc[6] = fmaf(xb.z, w, acc[6]);
            acc[7] = fmaf(xb.w, w, acc[7]);
        }
    }
#pragma unroll
    for (int j = 0; j < 8; ++j) {
        int n = n0 + y * 8 + j;
        if (n < N) H[(size_t)n * 96 + c] = acc[j];
    }
}

// ---------------- per-node attention coefficients ----------------
__global__ void att_kernel(const float* __restrict__ H,
                           const float* __restrict__ att_s,
                           const float* __restrict__ att_d,
                           float* __restrict__ a_s, float* __restrict__ a_d, int N)
{
    int t = blockIdx.x * blockDim.x + threadIdx.x;  // n*8 + h
    if (t >= N * NHEAD) return;
    int n = t >> 3, hh = t & 7;
    const float* hp = H + (size_t)n * DMODEL + hh * CDIM;
    float ss = 0.f, sd = 0.f;
#pragma unroll
    for (int ci = 0; ci < CDIM; ++ci) {
        float v = hp[ci];
        ss = fmaf(v, att_s[hh * CDIM + ci], ss);
        sd = fmaf(v, att_d[hh * CDIM + ci], sd);
    }
    a_s[t] = ss;
    a_d[t] = sd;
}

// ---------------- CSR build ----------------
__global__ void deg_kernel(const int* __restrict__ dsti, int* __restrict__ deg,
                           int E0, int Etot)
{
    int e = blockIdx.x * blockDim.x + threadIdx.x;
    if (e >= Etot) return;
    int d = (e < E0) ? dsti[e] : e - E0;
    atomicAdd(&deg[d], 1);
}

__global__ __launch_bounds__(1024) void scan_block_kernel(
    const int* __restrict__ deg, int* __restrict__ rowptr,
    int* __restrict__ bsum, int N)
{
    __shared__ int sh[1024];
    int t = threadIdx.x, g = blockIdx.x * 1024 + t;
    int v = (g < N) ? deg[g] : 0;
    sh[t] = v;
    __syncthreads();
    for (int off = 1; off < 1024; off <<= 1) {
        int add = (t >= off) ? sh[t - off] : 0;
        __syncthreads();
        sh[t] += add;
        __syncthreads();
    }
    if (g < N) rowptr[g] = sh[t] - v;   // exclusive scan
    if (t == 1023) bsum[blockIdx.x] = sh[t];
}

__global__ void scan_bsum_kernel(int* bsum, int nb)
{
    if (threadIdx.x == 0) {
        int acc = 0;
        for (int i = 0; i < nb; ++i) { int v = bsum[i]; bsum[i] = acc; acc += v; }
    }
}

__global__ void scan_add_kernel(int* __restrict__ rowptr, const int* __restrict__ bsum,
                                int N, int Etot)
{
    int g = blockIdx.x * blockDim.x + threadIdx.x;
    if (g < N) rowptr[g] += bsum[g >> 10];
    if (g == 0) rowptr[N] = Etot;
}

__global__ void scatter_kernel(const int* __restrict__ srci, const int* __restrict__ dsti,
                               int* __restrict__ cnt, int* __restrict__ col,
                               int E0, int Etot)
{
    int e = blockIdx.x * blockDim.x + threadIdx.x;
    if (e >= Etot) return;
    int s, d;
    if (e < E0) { s = srci[e]; d = dsti[e]; }
    else        { s = d = e - E0; }
    int pos = atomicAdd(&cnt[d], 1);
    col[pos] = s;
}

// ---------------- edge pass 1 (CSR): e_exp + denom, no atomics ----------------
__global__ void edge1_csr_kernel(const int* __restrict__ rowptr, const int* __restrict__ col,
                                 const float* __restrict__ a_s, const float* __restrict__ a_d,
                                 float* __restrict__ eexp, float* __restrict__ denom, int N)
{
    int t = blockIdx.x * blockDim.x + threadIdx.x;  // d*8 + h
    if (t >= N * NHEAD) return;
    int d = t >> 3, hh = t & 7;
    float ad = a_d[t];
    int j0 = rowptr[d], j1 = rowptr[d + 1];
    float den = 0.f;
    for (int j = j0; j < j1; ++j) {
        int s = col[j];
        float v = a_s[s * NHEAD + hh] + ad;
        v = v > 0.f ? v : 0.2f * v;      // leaky_relu
        float ex = __expf(v);
        eexp[(size_t)j * NHEAD + hh] = ex;
        den += ex;
    }
    denom[t] = den;
}

// ---------------- edge pass 2 (CSR): gather + fused bias/relu ----------------
__global__ __launch_bounds__(384) void edge2_csr_kernel(
    const int* __restrict__ rowptr, const int* __restrict__ col,
    const float* __restrict__ H, const float* __restrict__ eexp,
    const float* __restrict__ denom, const float* __restrict__ bias,
    float* __restrict__ out, int N)
{
    int d = blockIdx.x * 4 + threadIdx.x / 96;
    if (d >= N) return;
    int c = threadIdx.x % 96;
    int hh = c / CDIM;
    float den = denom[d * NHEAD + hh] + 1e-16f;
    int j0 = rowptr[d], j1 = rowptr[d + 1];
    float acc = 0.f;
    for (int j = j0; j < j1; ++j) {
        int s = col[j];
        float w = eexp[(size_t)j * NHEAD + hh];
        acc = fmaf(w, H[(size_t)s * DMODEL + c], acc);
    }
    float v = acc / den + bias[c];
    out[(size_t)d * DMODEL + c] = v > 0.f ? v : 0.f;
}

extern "C" void kernel_launch(void* const* d_in, const int* in_sizes, int n_in,
                              void* d_out, int out_size, void* d_ws, size_t ws_size,
                              hipStream_t stream) {
    const float* x   = (const float*)d_in[0];
    const int*   ei  = (const int*)d_in[1];
    const float* W1  = (const float*)d_in[2];
    const float* as1 = (const float*)d_in[3];
    const float* ad1 = (const float*)d_in[4];
    const float* b1  = (const float*)d_in[5];
    const float* W2  = (const float*)d_in[6];
    const float* as2 = (const float*)d_in[7];
    const float* ad2 = (const float*)d_in[8];
    const float* b2  = (const float*)d_in[9];

    const int N    = in_sizes[0] / 128;   // 50000
    const int E0   = in_sizes[1] / 2;     // 800000
    const int Etot = E0 + N;              // with self-loops
    const int* srci = ei;
    const int* dsti = ei + E0;

    // -------- workspace layout --------
    char* wsb = (char*)d_ws;
    float* H   = (float*)wsb;                 wsb += (size_t)N * DMODEL * 4;
    float* H1  = (float*)wsb;                 wsb += (size_t)N * DMODEL * 4;
    float* AS  = (float*)wsb;                 wsb += (size_t)N * NHEAD * 4;
    float* AD  = (float*)wsb;                 wsb += (size_t)N * NHEAD * 4;
    float* DEN = (float*)wsb;                 wsb += (size_t)N * NHEAD * 4;
    float* EE  = (float*)wsb;                 wsb += (size_t)Etot * NHEAD * 4;
    int* DEG   = (int*)wsb;                   wsb += (size_t)N * 4;
    int* ROWPTR= (int*)wsb;                   wsb += (size_t)(N + 1) * 4;
    int* CNT   = (int*)wsb;                   wsb += (size_t)N * 4;
    int* BSUM  = (int*)wsb;                   wsb += 256 * 4;
    int* COL   = (int*)wsb;                   wsb += (size_t)Etot * 4;
    float* OUT = (float*)d_out;

    const int nb_scan   = (N + 1023) / 1024;
    const int gemm_grid = (N + 15) / 16;
    const int att_grid  = (N * NHEAD + 255) / 256;
    const int e1_grid   = (N * NHEAD + 255) / 256;
    const int e2_grid   = (N + 3) / 4;
    const int edge_grid = (Etot + 255) / 256;

    // -------- CSR build (once, shared by both layers) --------
    hipMemsetAsync(DEG, 0, (size_t)N * 4, stream);
    deg_kernel<<<edge_grid, 256, 0, stream>>>(dsti, DEG, E0, Etot);
    scan_block_kernel<<<nb_scan, 1024, 0, stream>>>(DEG, ROWPTR, BSUM, N);
    scan_bsum_kernel<<<1, 64, 0, stream>>>(BSUM, nb_scan);
    scan_add_kernel<<<(N + 255) / 256, 256, 0, stream>>>(ROWPTR, BSUM, N, Etot);
    hipMemcpyAsync(CNT, ROWPTR, (size_t)N * 4, hipMemcpyDeviceToDevice, stream);
    scatter_kernel<<<edge_grid, 256, 0, stream>>>(srci, dsti, CNT, COL, E0, Etot);

    // -------- layer 1 --------
    gemm_att_kernel<128><<<gemm_grid, 192, 0, stream>>>(x, W1, H, N);
    att_kernel<<<att_grid, 256, 0, stream>>>(H, as1, ad1, AS, AD, N);
    edge1_csr_kernel<<<e1_grid, 256, 0, stream>>>(ROWPTR, COL, AS, AD, EE, DEN, N);
    edge2_csr_kernel<<<e2_grid, 384, 0, stream>>>(ROWPTR, COL, H, EE, DEN, b1, H1, N);

    // -------- layer 2 --------
    gemm_att_kernel<96><<<gemm_grid, 192, 0, stream>>>(H1, W2, H, N);
    att_kernel<<<att_grid, 256, 0, stream>>>(H, as2, ad2, AS, AD, N);
    edge1_csr_kernel<<<e1_grid, 256, 0, stream>>>(ROWPTR, COL, AS, AD, EE, DEN, N);
    edge2_csr_kernel<<<e2_grid, 384, 0, stream>>>(ROWPTR, COL, H, EE, DEN, b2, OUT, N);
}

// Round 3
// 363.201 us; speedup vs baseline: 2.3170x; 1.5275x over previous
//
#include <hip/hip_runtime.h>
#include <hip/hip_bf16.h>

#define NHEAD 8
#define CDIM 12
#define DMODEL 96

// ---------------- GEMM: H[N,96] = X[N,K] @ W[K,96] ----------------
template<int K>
__global__ __launch_bounds__(192) void gemm_att_kernel(
    const float* __restrict__ X, const float* __restrict__ W,
    float* __restrict__ H, int N)
{
    __shared__ float xs[K][16];
    __shared__ float wsh[32 * 96];
    const int t = threadIdx.x;
    const int c = t % 96;
    const int y = t / 96;
    const int n0 = blockIdx.x * 16;

    constexpr int KQ = K / 4;
    for (int e = t; e < 16 * KQ; e += 192) {
        int i = e / KQ, kq = e % KQ;
        int n = n0 + i;
        float4 v = make_float4(0.f, 0.f, 0.f, 0.f);
        if (n < N) v = ((const float4*)(X + (size_t)n * K))[kq];
        xs[kq * 4 + 0][i] = v.x;
        xs[kq * 4 + 1][i] = v.y;
        xs[kq * 4 + 2][i] = v.z;
        xs[kq * 4 + 3][i] = v.w;
    }

    float acc[8] = {0.f,0.f,0.f,0.f,0.f,0.f,0.f,0.f};
    for (int k0 = 0; k0 < K; k0 += 32) {
        __syncthreads();
        for (int e = t; e < 768; e += 192)
            ((float4*)wsh)[e] = ((const float4*)(W + (size_t)k0 * 96))[e];
        __syncthreads();
#pragma unroll
        for (int kk = 0; kk < 32; ++kk) {
            int k = k0 + kk;
            float w = wsh[kk * 96 + c];
            float4 xa = *(const float4*)&xs[k][y * 8];
            float4 xb = *(const float4*)&xs[k][y * 8 + 4];
            acc[0] = fmaf(xa.x, w, acc[0]);
            acc[1] = fmaf(xa.y, w, acc[1]);
            acc[2] = fmaf(xa.z, w, acc[2]);
            acc[3] = fmaf(xa.w, w, acc[3]);
            acc[4] = fmaf(xb.x, w, acc[4]);
            acc[5] = fmaf(xb.y, w, acc[5]);
            acc[6] = fmaf(xb.z, w, acc[6]);
            acc[7] = fmaf(xb.w, w, acc[7]);
        }
    }
#pragma unroll
    for (int j = 0; j < 8; ++j) {
        int n = n0 + y * 8 + j;
        if (n < N) H[(size_t)n * 96 + c] = acc[j];
    }
}

// ---------------- per-node attention coefficients ----------------
__global__ void att_kernel(const float* __restrict__ H,
                           const float* __restrict__ att_s,
                           const float* __restrict__ att_d,
                           float* __restrict__ a_s, float* __restrict__ a_d, int N)
{
    int t = blockIdx.x * blockDim.x + threadIdx.x;  // n*8 + h
    if (t >= N * NHEAD) return;
    int n = t >> 3, hh = t & 7;
    const float* hp = H + (size_t)n * DMODEL + hh * CDIM;
    float ss = 0.f, sd = 0.f;
#pragma unroll
    for (int ci = 0; ci < CDIM; ++ci) {
        float v = hp[ci];
        ss = fmaf(v, att_s[hh * CDIM + ci], ss);
        sd = fmaf(v, att_d[hh * CDIM + ci], sd);
    }
    a_s[t] = ss;
    a_d[t] = sd;
}

// ---------------- CSR build ----------------
__global__ void deg_kernel(const int* __restrict__ dsti, int* __restrict__ deg,
                           int E0, int Etot)
{
    int e = blockIdx.x * blockDim.x + threadIdx.x;
    if (e >= Etot) return;
    int d = (e < E0) ? dsti[e] : e - E0;
    atomicAdd(&deg[d], 1);
}

__global__ __launch_bounds__(1024) void scan_block_kernel(
    const int* __restrict__ deg, int* __restrict__ rowptr,
    int* __restrict__ bsum, int N)
{
    __shared__ int sh[1024];
    int t = threadIdx.x, g = blockIdx.x * 1024 + t;
    int v = (g < N) ? deg[g] : 0;
    sh[t] = v;
    __syncthreads();
    for (int off = 1; off < 1024; off <<= 1) {
        int add = (t >= off) ? sh[t - off] : 0;
        __syncthreads();
        sh[t] += add;
        __syncthreads();
    }
    if (g < N) rowptr[g] = sh[t] - v;   // exclusive scan
    if (t == 1023) bsum[blockIdx.x] = sh[t];
}

__global__ void scan_bsum_kernel(int* bsum, int nb)
{
    if (threadIdx.x == 0) {
        int acc = 0;
        for (int i = 0; i < nb; ++i) { int v = bsum[i]; bsum[i] = acc; acc += v; }
    }
}

__global__ void scan_add_kernel(int* __restrict__ rowptr, const int* __restrict__ bsum,
                                int N, int Etot)
{
    int g = blockIdx.x * blockDim.x + threadIdx.x;
    if (g < N) rowptr[g] += bsum[g >> 10];
    if (g == 0) rowptr[N] = Etot;
}

__global__ void scatter_kernel(const int* __restrict__ srci, const int* __restrict__ dsti,
                               int* __restrict__ cnt, int* __restrict__ col,
                               int E0, int Etot)
{
    int e = blockIdx.x * blockDim.x + threadIdx.x;
    if (e >= Etot) return;
    int s, d;
    if (e < E0) { s = srci[e]; d = dsti[e]; }
    else        { s = d = e - E0; }
    int pos = atomicAdd(&cnt[d], 1);
    col[pos] = s;
}

// ---------------- edge pass 1 (CSR): denom only, 4x unrolled ----------------
__global__ void edge1_csr_kernel(const int* __restrict__ rowptr, const int* __restrict__ col,
                                 const float* __restrict__ a_s, const float* __restrict__ a_d,
                                 float* __restrict__ denom, int N)
{
    int t = blockIdx.x * blockDim.x + threadIdx.x;  // d*8 + h
    if (t >= N * NHEAD) return;
    int d = t >> 3, hh = t & 7;
    float ad = a_d[t];
    int j0 = rowptr[d], j1 = rowptr[d + 1];
    float den = 0.f;
    int j = j0;
    for (; j + 3 < j1; j += 4) {
        int s0 = col[j], s1 = col[j+1], s2 = col[j+2], s3 = col[j+3];
        float v0 = a_s[s0 * NHEAD + hh] + ad;
        float v1 = a_s[s1 * NHEAD + hh] + ad;
        float v2 = a_s[s2 * NHEAD + hh] + ad;
        float v3 = a_s[s3 * NHEAD + hh] + ad;
        v0 = v0 > 0.f ? v0 : 0.2f * v0;
        v1 = v1 > 0.f ? v1 : 0.2f * v1;
        v2 = v2 > 0.f ? v2 : 0.2f * v2;
        v3 = v3 > 0.f ? v3 : 0.2f * v3;
        den += __expf(v0) + __expf(v1) + __expf(v2) + __expf(v3);
    }
    for (; j < j1; ++j) {
        int s = col[j];
        float v = a_s[s * NHEAD + hh] + ad;
        v = v > 0.f ? v : 0.2f * v;
        den += __expf(v);
    }
    denom[t] = den;
}

// ---------------- edge pass 2 (CSR): float4 gather, exp recompute, 4x unroll ----------------
__global__ __launch_bounds__(384) void edge2_vec_kernel(
    const int* __restrict__ rowptr, const int* __restrict__ col,
    const float* __restrict__ H, const float* __restrict__ a_s,
    const float* __restrict__ a_d, const float* __restrict__ denom,
    const float* __restrict__ bias, float* __restrict__ out, int N)
{
    const int grp  = threadIdx.x / 24;      // node within block (16 nodes/block)
    const int lane = threadIdx.x % 24;      // float4 chunk 0..23
    const int d = blockIdx.x * 16 + grp;
    if (d >= N) return;
    const int hh = (lane * 4) / CDIM;       // head of this chunk
    const float ad  = a_d[d * NHEAD + hh];
    const float den = denom[d * NHEAD + hh] + 1e-16f;
    const float4* __restrict__ H4 = (const float4*)H;

    int j0 = rowptr[d], j1 = rowptr[d + 1];
    float4 acc = make_float4(0.f, 0.f, 0.f, 0.f);
    int j = j0;
    for (; j + 3 < j1; j += 4) {
        int s0 = col[j], s1 = col[j+1], s2 = col[j+2], s3 = col[j+3];
        float v0 = a_s[s0 * NHEAD + hh] + ad;
        float v1 = a_s[s1 * NHEAD + hh] + ad;
        float v2 = a_s[s2 * NHEAD + hh] + ad;
        float v3 = a_s[s3 * NHEAD + hh] + ad;
        float4 h0 = H4[(size_t)s0 * 24 + lane];
        float4 h1 = H4[(size_t)s1 * 24 + lane];
        float4 h2 = H4[(size_t)s2 * 24 + lane];
        float4 h3 = H4[(size_t)s3 * 24 + lane];
        v0 = v0 > 0.f ? v0 : 0.2f * v0;
        v1 = v1 > 0.f ? v1 : 0.2f * v1;
        v2 = v2 > 0.f ? v2 : 0.2f * v2;
        v3 = v3 > 0.f ? v3 : 0.2f * v3;
        float e0 = __expf(v0), e1 = __expf(v1), e2 = __expf(v2), e3 = __expf(v3);
        acc.x = fmaf(e0, h0.x, acc.x); acc.y = fmaf(e0, h0.y, acc.y);
        acc.z = fmaf(e0, h0.z, acc.z); acc.w = fmaf(e0, h0.w, acc.w);
        acc.x = fmaf(e1, h1.x, acc.x); acc.y = fmaf(e1, h1.y, acc.y);
        acc.z = fmaf(e1, h1.z, acc.z); acc.w = fmaf(e1, h1.w, acc.w);
        acc.x = fmaf(e2, h2.x, acc.x); acc.y = fmaf(e2, h2.y, acc.y);
        acc.z = fmaf(e2, h2.z, acc.z); acc.w = fmaf(e2, h2.w, acc.w);
        acc.x = fmaf(e3, h3.x, acc.x); acc.y = fmaf(e3, h3.y, acc.y);
        acc.z = fmaf(e3, h3.z, acc.z); acc.w = fmaf(e3, h3.w, acc.w);
    }
    for (; j < j1; ++j) {
        int s = col[j];
        float v = a_s[s * NHEAD + hh] + ad;
        v = v > 0.f ? v : 0.2f * v;
        float ex = __expf(v);
        float4 hv = H4[(size_t)s * 24 + lane];
        acc.x = fmaf(ex, hv.x, acc.x); acc.y = fmaf(ex, hv.y, acc.y);
        acc.z = fmaf(ex, hv.z, acc.z); acc.w = fmaf(ex, hv.w, acc.w);
    }
    float inv = 1.0f / den;
    float4 bv = ((const float4*)bias)[lane];
    float4 o;
    o.x = fmaf(acc.x, inv, bv.x); o.y = fmaf(acc.y, inv, bv.y);
    o.z = fmaf(acc.z, inv, bv.z); o.w = fmaf(acc.w, inv, bv.w);
    o.x = o.x > 0.f ? o.x : 0.f;  o.y = o.y > 0.f ? o.y : 0.f;
    o.z = o.z > 0.f ? o.z : 0.f;  o.w = o.w > 0.f ? o.w : 0.f;
    ((float4*)out)[(size_t)d * 24 + lane] = o;
}

extern "C" void kernel_launch(void* const* d_in, const int* in_sizes, int n_in,
                              void* d_out, int out_size, void* d_ws, size_t ws_size,
                              hipStream_t stream) {
    const float* x   = (const float*)d_in[0];
    const int*   ei  = (const int*)d_in[1];
    const float* W1  = (const float*)d_in[2];
    const float* as1 = (const float*)d_in[3];
    const float* ad1 = (const float*)d_in[4];
    const float* b1  = (const float*)d_in[5];
    const float* W2  = (const float*)d_in[6];
    const float* as2 = (const float*)d_in[7];
    const float* ad2 = (const float*)d_in[8];
    const float* b2  = (const float*)d_in[9];

    const int N    = in_sizes[0] / 128;   // 50000
    const int E0   = in_sizes[1] / 2;     // 800000
    const int Etot = E0 + N;              // with self-loops
    const int* srci = ei;
    const int* dsti = ei + E0;

    // -------- workspace layout --------
    char* wsb = (char*)d_ws;
    float* H   = (float*)wsb;                 wsb += (size_t)N * DMODEL * 4;
    float* H1  = (float*)wsb;                 wsb += (size_t)N * DMODEL * 4;
    float* AS  = (float*)wsb;                 wsb += (size_t)N * NHEAD * 4;
    float* AD  = (float*)wsb;                 wsb += (size_t)N * NHEAD * 4;
    float* DEN = (float*)wsb;                 wsb += (size_t)N * NHEAD * 4;
    int* DEG   = (int*)wsb;                   wsb += (size_t)N * 4;
    int* ROWPTR= (int*)wsb;                   wsb += (size_t)(N + 1) * 4;
    int* CNT   = (int*)wsb;                   wsb += (size_t)N * 4;
    int* BSUM  = (int*)wsb;                   wsb += 256 * 4;
    int* COL   = (int*)wsb;                   wsb += (size_t)Etot * 4;
    float* OUT = (float*)d_out;

    const int nb_scan   = (N + 1023) / 1024;
    const int gemm_grid = (N + 15) / 16;
    const int att_grid  = (N * NHEAD + 255) / 256;
    const int e1_grid   = (N * NHEAD + 255) / 256;
    const int e2_grid   = (N + 15) / 16;
    const int edge_grid = (Etot + 255) / 256;

    // -------- CSR build (once, shared by both layers) --------
    hipMemsetAsync(DEG, 0, (size_t)N * 4, stream);
    deg_kernel<<<edge_grid, 256, 0, stream>>>(dsti, DEG, E0, Etot);
    scan_block_kernel<<<nb_scan, 1024, 0, stream>>>(DEG, ROWPTR, BSUM, N);
    scan_bsum_kernel<<<1, 64, 0, stream>>>(BSUM, nb_scan);
    scan_add_kernel<<<(N + 255) / 256, 256, 0, stream>>>(ROWPTR, BSUM, N, Etot);
    hipMemcpyAsync(CNT, ROWPTR, (size_t)N * 4, hipMemcpyDeviceToDevice, stream);
    scatter_kernel<<<edge_grid, 256, 0, stream>>>(srci, dsti, CNT, COL, E0, Etot);

    // -------- layer 1 --------
    gemm_att_kernel<128><<<gemm_grid, 192, 0, stream>>>(x, W1, H, N);
    att_kernel<<<att_grid, 256, 0, stream>>>(H, as1, ad1, AS, AD, N);
    edge1_csr_kernel<<<e1_grid, 256, 0, stream>>>(ROWPTR, COL, AS, AD, DEN, N);
    edge2_vec_kernel<<<e2_grid, 384, 0, stream>>>(ROWPTR, COL, H, AS, AD, DEN, b1, H1, N);

    // -------- layer 2 --------
    gemm_att_kernel<96><<<gemm_grid, 192, 0, stream>>>(H1, W2, H, N);
    att_kernel<<<att_grid, 256, 0, stream>>>(H, as2, ad2, AS, AD, N);
    edge1_csr_kernel<<<e1_grid, 256, 0, stream>>>(ROWPTR, COL, AS, AD, DEN, N);
    edge2_vec_kernel<<<e2_grid, 384, 0, stream>>>(ROWPTR, COL, H, AS, AD, DEN, b2, OUT, N);
}

// Round 4
// 315.958 us; speedup vs baseline: 2.6634x; 1.1495x over previous
//
#include <hip/hip_runtime.h>
#include <hip/hip_bf16.h>

#define NHEAD 8
#define CDIM 12
#define DMODEL 96

// ---------------- fused GEMM + attention coefficients ----------------
// H[N,96] = X[N,K] @ W[K,96];  a_s[n,h] = dot(h[n,h,:], att_s[h,:]);  same a_d.
// block: 192 threads = (c4 = t/8 in 0..23, y = t%8 in 0..7); 32 nodes/block.
// Each thread: 4 nodes (4y..4y+3) x 4 cols (4c4..4c4+3) register tile.
template<int K>
__global__ __launch_bounds__(192) void gemm_att_fused(
    const float* __restrict__ X, const float* __restrict__ W,
    const float* __restrict__ att_s, const float* __restrict__ att_d,
    float* __restrict__ H, float* __restrict__ a_s, float* __restrict__ a_d,
    int N)
{
    constexpr int KQ = K / 4;
    __shared__ float xs[K][40];        // X^T tile, swizzled cols, row stride 40
    __shared__ float wsh[64 * 96];     // W chunk (64 rows)
    __shared__ float red[32][16];      // [node][head*2 + (s|d)]
    const int t  = threadIdx.x;
    const int c4 = t / 8;              // 0..23  (float4 col chunk)
    const int y  = t % 8;              // 0..7   (node group)
    const int n0 = blockIdx.x * 32;

    // zero att reduction buffer
    for (int e = t; e < 512; e += 192) ((float*)red)[e] = 0.f;

    // stage X tile, transposed, XOR-swizzled (coalesced 512B global reads)
    for (int e = t; e < 32 * KQ; e += 192) {
        int n = e / KQ, kq = e % KQ;
        int gn = n0 + n;
        float4 v = make_float4(0.f, 0.f, 0.f, 0.f);
        if (gn < N) v = ((const float4*)(X + (size_t)gn * K))[kq];
        int ncol = n ^ ((kq & 7) << 2);
        xs[4 * kq + 0][ncol] = v.x;
        xs[4 * kq + 1][ncol] = v.y;
        xs[4 * kq + 2][ncol] = v.z;
        xs[4 * kq + 3][ncol] = v.w;
    }

    float4 acc[4];
#pragma unroll
    for (int i = 0; i < 4; ++i) acc[i] = make_float4(0.f, 0.f, 0.f, 0.f);

    for (int k0 = 0; k0 < K; k0 += 64) {
        const int kc = (K - k0 < 64) ? (K - k0) : 64;
        __syncthreads();
        for (int e = t; e < kc * 24; e += 192)
            ((float4*)wsh)[e] = ((const float4*)(W + (size_t)k0 * 96))[e];
        __syncthreads();
#pragma unroll 4
        for (int kk = 0; kk < kc; ++kk) {
            const int k = k0 + kk;
            const float4 wv = *(const float4*)&wsh[kk * 96 + c4 * 4];
            const int q = (k >> 2) & 7;
            const float4 xv = *(const float4*)&xs[k][4 * (y ^ q)];
            acc[0].x = fmaf(xv.x, wv.x, acc[0].x);
            acc[0].y = fmaf(xv.x, wv.y, acc[0].y);
            acc[0].z = fmaf(xv.x, wv.z, acc[0].z);
            acc[0].w = fmaf(xv.x, wv.w, acc[0].w);
            acc[1].x = fmaf(xv.y, wv.x, acc[1].x);
            acc[1].y = fmaf(xv.y, wv.y, acc[1].y);
            acc[1].z = fmaf(xv.y, wv.z, acc[1].z);
            acc[1].w = fmaf(xv.y, wv.w, acc[1].w);
            acc[2].x = fmaf(xv.z, wv.x, acc[2].x);
            acc[2].y = fmaf(xv.z, wv.y, acc[2].y);
            acc[2].z = fmaf(xv.z, wv.z, acc[2].z);
            acc[2].w = fmaf(xv.z, wv.w, acc[2].w);
            acc[3].x = fmaf(xv.w, wv.x, acc[3].x);
            acc[3].y = fmaf(xv.w, wv.y, acc[3].y);
            acc[3].z = fmaf(xv.w, wv.z, acc[3].z);
            acc[3].w = fmaf(xv.w, wv.w, acc[3].w);
        }
    }

    // ---- fused attention-coefficient partials ----
    const int h = c4 / 3;                       // head of this col chunk
    const float4 asv = ((const float4*)att_s)[c4];
    const float4 adv = ((const float4*)att_d)[c4];
#pragma unroll
    for (int i = 0; i < 4; ++i) {
        const int m = 4 * y + i;                // local node
        float ps = acc[i].x * asv.x + acc[i].y * asv.y
                 + acc[i].z * asv.z + acc[i].w * asv.w;
        float pd = acc[i].x * adv.x + acc[i].y * adv.y
                 + acc[i].z * adv.z + acc[i].w * adv.w;
        atomicAdd(&red[m][h * 2 + 0], ps);
        atomicAdd(&red[m][h * 2 + 1], pd);
    }

    // ---- H store (128B contiguous per 8 lanes) ----
#pragma unroll
    for (int i = 0; i < 4; ++i) {
        const int gn = n0 + 4 * y + i;
        if (gn < N) ((float4*)(H + (size_t)gn * 96))[c4] = acc[i];
    }

    __syncthreads();
    for (int e = t; e < 256; e += 192) {
        const int m = e >> 3, hh = e & 7;
        const int gn = n0 + m;
        if (gn < N) {
            a_s[gn * NHEAD + hh] = red[m][hh * 2 + 0];
            a_d[gn * NHEAD + hh] = red[m][hh * 2 + 1];
        }
    }
}

// ---------------- CSR build ----------------
__global__ void deg_kernel(const int* __restrict__ dsti, int* __restrict__ deg,
                           int E0, int Etot)
{
    int e = blockIdx.x * blockDim.x + threadIdx.x;
    if (e >= Etot) return;
    int d = (e < E0) ? dsti[e] : e - E0;
    atomicAdd(&deg[d], 1);
}

__global__ __launch_bounds__(1024) void scan_block_kernel(
    const int* __restrict__ deg, int* __restrict__ rowptr,
    int* __restrict__ bsum, int N)
{
    __shared__ int sh[1024];
    int t = threadIdx.x, g = blockIdx.x * 1024 + t;
    int v = (g < N) ? deg[g] : 0;
    sh[t] = v;
    __syncthreads();
    for (int off = 1; off < 1024; off <<= 1) {
        int add = (t >= off) ? sh[t - off] : 0;
        __syncthreads();
        sh[t] += add;
        __syncthreads();
    }
    if (g < N) rowptr[g] = sh[t] - v;   // exclusive scan
    if (t == 1023) bsum[blockIdx.x] = sh[t];
}

__global__ void scan_bsum_kernel(int* bsum, int nb)
{
    if (threadIdx.x == 0) {
        int acc = 0;
        for (int i = 0; i < nb; ++i) { int v = bsum[i]; bsum[i] = acc; acc += v; }
    }
}

__global__ void scan_add_kernel(int* __restrict__ rowptr, const int* __restrict__ bsum,
                                int N, int Etot)
{
    int g = blockIdx.x * blockDim.x + threadIdx.x;
    if (g < N) rowptr[g] += bsum[g >> 10];
    if (g == 0) rowptr[N] = Etot;
}

__global__ void scatter_kernel(const int* __restrict__ srci, const int* __restrict__ dsti,
                               int* __restrict__ cnt, int* __restrict__ col,
                               int E0, int Etot)
{
    int e = blockIdx.x * blockDim.x + threadIdx.x;
    if (e >= Etot) return;
    int s, d;
    if (e < E0) { s = srci[e]; d = dsti[e]; }
    else        { s = d = e - E0; }
    int pos = atomicAdd(&cnt[d], 1);
    col[pos] = s;
}

// ---------------- edge pass 1 (CSR): denom only, 4x unrolled ----------------
__global__ void edge1_csr_kernel(const int* __restrict__ rowptr, const int* __restrict__ col,
                                 const float* __restrict__ a_s, const float* __restrict__ a_d,
                                 float* __restrict__ denom, int N)
{
    int t = blockIdx.x * blockDim.x + threadIdx.x;  // d*8 + h
    if (t >= N * NHEAD) return;
    int d = t >> 3, hh = t & 7;
    float ad = a_d[t];
    int j0 = rowptr[d], j1 = rowptr[d + 1];
    float den = 0.f;
    int j = j0;
    for (; j + 3 < j1; j += 4) {
        int s0 = col[j], s1 = col[j+1], s2 = col[j+2], s3 = col[j+3];
        float v0 = a_s[s0 * NHEAD + hh] + ad;
        float v1 = a_s[s1 * NHEAD + hh] + ad;
        float v2 = a_s[s2 * NHEAD + hh] + ad;
        float v3 = a_s[s3 * NHEAD + hh] + ad;
        v0 = v0 > 0.f ? v0 : 0.2f * v0;
        v1 = v1 > 0.f ? v1 : 0.2f * v1;
        v2 = v2 > 0.f ? v2 : 0.2f * v2;
        v3 = v3 > 0.f ? v3 : 0.2f * v3;
        den += __expf(v0) + __expf(v1) + __expf(v2) + __expf(v3);
    }
    for (; j < j1; ++j) {
        int s = col[j];
        float v = a_s[s * NHEAD + hh] + ad;
        v = v > 0.f ? v : 0.2f * v;
        den += __expf(v);
    }
    denom[t] = den;
}

// ---------------- edge pass 2 (CSR): float4 gather, exp recompute, 4x unroll ----------------
__global__ __launch_bounds__(384) void edge2_vec_kernel(
    const int* __restrict__ rowptr, const int* __restrict__ col,
    const float* __restrict__ H, const float* __restrict__ a_s,
    const float* __restrict__ a_d, const float* __restrict__ denom,
    const float* __restrict__ bias, float* __restrict__ out, int N)
{
    const int grp  = threadIdx.x / 24;      // node within block (16 nodes/block)
    const int lane = threadIdx.x % 24;      // float4 chunk 0..23
    const int d = blockIdx.x * 16 + grp;
    if (d >= N) return;
    const int hh = (lane * 4) / CDIM;       // head of this chunk
    const float ad  = a_d[d * NHEAD + hh];
    const float den = denom[d * NHEAD + hh] + 1e-16f;
    const float4* __restrict__ H4 = (const float4*)H;

    int j0 = rowptr[d], j1 = rowptr[d + 1];
    float4 acc = make_float4(0.f, 0.f, 0.f, 0.f);
    int j = j0;
    for (; j + 3 < j1; j += 4) {
        int s0 = col[j], s1 = col[j+1], s2 = col[j+2], s3 = col[j+3];
        float v0 = a_s[s0 * NHEAD + hh] + ad;
        float v1 = a_s[s1 * NHEAD + hh] + ad;
        float v2 = a_s[s2 * NHEAD + hh] + ad;
        float v3 = a_s[s3 * NHEAD + hh] + ad;
        float4 h0 = H4[(size_t)s0 * 24 + lane];
        float4 h1 = H4[(size_t)s1 * 24 + lane];
        float4 h2 = H4[(size_t)s2 * 24 + lane];
        float4 h3 = H4[(size_t)s3 * 24 + lane];
        v0 = v0 > 0.f ? v0 : 0.2f * v0;
        v1 = v1 > 0.f ? v1 : 0.2f * v1;
        v2 = v2 > 0.f ? v2 : 0.2f * v2;
        v3 = v3 > 0.f ? v3 : 0.2f * v3;
        float e0 = __expf(v0), e1 = __expf(v1), e2 = __expf(v2), e3 = __expf(v3);
        acc.x = fmaf(e0, h0.x, acc.x); acc.y = fmaf(e0, h0.y, acc.y);
        acc.z = fmaf(e0, h0.z, acc.z); acc.w = fmaf(e0, h0.w, acc.w);
        acc.x = fmaf(e1, h1.x, acc.x); acc.y = fmaf(e1, h1.y, acc.y);
        acc.z = fmaf(e1, h1.z, acc.z); acc.w = fmaf(e1, h1.w, acc.w);
        acc.x = fmaf(e2, h2.x, acc.x); acc.y = fmaf(e2, h2.y, acc.y);
        acc.z = fmaf(e2, h2.z, acc.z); acc.w = fmaf(e2, h2.w, acc.w);
        acc.x = fmaf(e3, h3.x, acc.x); acc.y = fmaf(e3, h3.y, acc.y);
        acc.z = fmaf(e3, h3.z, acc.z); acc.w = fmaf(e3, h3.w, acc.w);
    }
    for (; j < j1; ++j) {
        int s = col[j];
        float v = a_s[s * NHEAD + hh] + ad;
        v = v > 0.f ? v : 0.2f * v;
        float ex = __expf(v);
        float4 hv = H4[(size_t)s * 24 + lane];
        acc.x = fmaf(ex, hv.x, acc.x); acc.y = fmaf(ex, hv.y, acc.y);
        acc.z = fmaf(ex, hv.z, acc.z); acc.w = fmaf(ex, hv.w, acc.w);
    }
    float inv = 1.0f / den;
    float4 bv = ((const float4*)bias)[lane];
    float4 o;
    o.x = fmaf(acc.x, inv, bv.x); o.y = fmaf(acc.y, inv, bv.y);
    o.z = fmaf(acc.z, inv, bv.z); o.w = fmaf(acc.w, inv, bv.w);
    o.x = o.x > 0.f ? o.x : 0.f;  o.y = o.y > 0.f ? o.y : 0.f;
    o.z = o.z > 0.f ? o.z : 0.f;  o.w = o.w > 0.f ? o.w : 0.f;
    ((float4*)out)[(size_t)d * 24 + lane] = o;
}

extern "C" void kernel_launch(void* const* d_in, const int* in_sizes, int n_in,
                              void* d_out, int out_size, void* d_ws, size_t ws_size,
                              hipStream_t stream) {
    const float* x   = (const float*)d_in[0];
    const int*   ei  = (const int*)d_in[1];
    const float* W1  = (const float*)d_in[2];
    const float* as1 = (const float*)d_in[3];
    const float* ad1 = (const float*)d_in[4];
    const float* b1  = (const float*)d_in[5];
    const float* W2  = (const float*)d_in[6];
    const float* as2 = (const float*)d_in[7];
    const float* ad2 = (const float*)d_in[8];
    const float* b2  = (const float*)d_in[9];

    const int N    = in_sizes[0] / 128;   // 50000
    const int E0   = in_sizes[1] / 2;     // 800000
    const int Etot = E0 + N;              // with self-loops
    const int* srci = ei;
    const int* dsti = ei + E0;

    // -------- workspace layout --------
    char* wsb = (char*)d_ws;
    float* H   = (float*)wsb;                 wsb += (size_t)N * DMODEL * 4;
    float* H1  = (float*)wsb;                 wsb += (size_t)N * DMODEL * 4;
    float* AS  = (float*)wsb;                 wsb += (size_t)N * NHEAD * 4;
    float* AD  = (float*)wsb;                 wsb += (size_t)N * NHEAD * 4;
    float* DEN = (float*)wsb;                 wsb += (size_t)N * NHEAD * 4;
    int* DEG   = (int*)wsb;                   wsb += (size_t)N * 4;
    int* ROWPTR= (int*)wsb;                   wsb += (size_t)(N + 1) * 4;
    int* CNT   = (int*)wsb;                   wsb += (size_t)N * 4;
    int* BSUM  = (int*)wsb;                   wsb += 256 * 4;
    int* COL   = (int*)wsb;                   wsb += (size_t)Etot * 4;
    float* OUT = (float*)d_out;

    const int nb_scan   = (N + 1023) / 1024;
    const int gemm_grid = (N + 31) / 32;
    const int e1_grid   = (N * NHEAD + 255) / 256;
    const int e2_grid   = (N + 15) / 16;
    const int edge_grid = (Etot + 255) / 256;

    // -------- CSR build (once, shared by both layers) --------
    hipMemsetAsync(DEG, 0, (size_t)N * 4, stream);
    deg_kernel<<<edge_grid, 256, 0, stream>>>(dsti, DEG, E0, Etot);
    scan_block_kernel<<<nb_scan, 1024, 0, stream>>>(DEG, ROWPTR, BSUM, N);
    scan_bsum_kernel<<<1, 64, 0, stream>>>(BSUM, nb_scan);
    scan_add_kernel<<<(N + 255) / 256, 256, 0, stream>>>(ROWPTR, BSUM, N, Etot);
    hipMemcpyAsync(CNT, ROWPTR, (size_t)N * 4, hipMemcpyDeviceToDevice, stream);
    scatter_kernel<<<edge_grid, 256, 0, stream>>>(srci, dsti, CNT, COL, E0, Etot);

    // -------- layer 1 --------
    gemm_att_fused<128><<<gemm_grid, 192, 0, stream>>>(x, W1, as1, ad1, H, AS, AD, N);
    edge1_csr_kernel<<<e1_grid, 256, 0, stream>>>(ROWPTR, COL, AS, AD, DEN, N);
    edge2_vec_kernel<<<e2_grid, 384, 0, stream>>>(ROWPTR, COL, H, AS, AD, DEN, b1, H1, N);

    // -------- layer 2 --------
    gemm_att_fused<96><<<gemm_grid, 192, 0, stream>>>(H1, W2, as2, ad2, H, AS, AD, N);
    edge1_csr_kernel<<<e1_grid, 256, 0, stream>>>(ROWPTR, COL, AS, AD, DEN, N);
    edge2_vec_kernel<<<e2_grid, 384, 0, stream>>>(ROWPTR, COL, H, AS, AD, DEN, b2, OUT, N);
}